// Round 12
// baseline (170.182 us; speedup 1.0000x reference)
//
#include <hip/hip_runtime.h>
#include <cstdint>
#include <cstddef>

#define NPTS 8192
#define NUM_CLASSES 5
#define XCOLS 10          // 3 coords + batch + feat + 5 seg
#define EPS2 225.0f
#define MIN_PTS 5
#define NGROUPS 10
#define BIGC 0x3fffffff

#define NLCAP 1536        // max nodes per group (expect ~820)
#define EACAP 8192        // all same-group eps-pairs u<v (expect ~5k)
#define ELCAP 8192        // core-core edges
#define EBCAP 2048        // core-noncore edges (expect ~500)
#define ROUNDS 24

// ---------------- setup: pack coords+p2, compute group ----------------
__global__ void k_setup(const float* __restrict__ x, float4* __restrict__ q,
                        int* __restrict__ grp) {
    int i = blockIdx.x * blockDim.x + threadIdx.x;
    if (i >= NPTS) return;
    const float* r = x + (size_t)i * XCOLS;
    float px = r[0], py = r[1], pz = r[2];
    int b = (int)r[3];
    float best = r[5]; int bc = 0;
    #pragma unroll
    for (int c = 1; c < NUM_CLASSES; c++) {
        float v = r[5 + c];
        if (v > best) { best = v; bc = c; }   // strict > keeps first max (jnp.argmax)
    }
    q[i] = make_float4(px, py, pz, px*px + py*py + pz*pz);
    grp[i] = b * NUM_CLASSES + bc;
}

// ---- pair strip: rows srow+r0+128k (k<KRN), replica-owned column chunks ----
// All register arrays compile-time indexed; strip guards are wave-uniform.
template<int KRN>
__device__ __forceinline__ void pair_strip(
        const float4* pts, unsigned int* eAll, int* sdeg, int* nAllp,
        int srow, int NC, int ROWSPAN, int rep, int r0, int lane) {
    float4 qu[KRN]; int rowdeg[KRN];
    #pragma unroll
    for (int k = 0; k < KRN; k++) {
        qu[k] = pts[srow + r0 + 128 * k];            // sentinel-padded: safe
        rowdeg[k] = 0;
    }
    for (int c = rep; c < NC; c += 8) {
        int base = c << 5;
        unsigned int bits[KRN];
        #pragma unroll
        for (int k = 0; k < KRN; k++) bits[k] = 0u;
        #pragma unroll
        for (int t = 0; t < 32; t++) {
            float4 qv = pts[base + t];               // wave-uniform -> LDS broadcast
            #pragma unroll
            for (int k = 0; k < KRN; k++) {
                if (srow + 128 * k < ROWSPAN) {      // uniform strip guard
                    float d2 = qu[k].w + qv.w - 2.0f * (qu[k].x*qv.x + qu[k].y*qv.y + qu[k].z*qv.z);
                    bits[k] |= (d2 < EPS2) ? (1u << t) : 0u;
                }
            }
        }
        int cnt = 0;
        #pragma unroll
        for (int k = 0; k < KRN; k++) {
            if (srow + 128 * k < ROWSPAN) {
                int d = (srow + r0 + 128 * k) - base;    // keep only v > u
                if (d >= 31) bits[k] = 0u;
                else if (d >= 0) bits[k] &= ~((2u << d) - 1u);
                int pc = __popc(bits[k]);
                rowdeg[k] += pc;
                cnt += pc;
            }
        }
        // wave-aggregated reservation (one LDS atomic per wave-chunk)
        int incl = cnt;
        #pragma unroll
        for (int st = 1; st < 64; st <<= 1) {
            int o = __shfl_up(incl, st);
            if (lane >= st) incl += o;
        }
        int tot = __shfl(incl, 63);
        if (tot > 0) {
            int rbase = 0;
            if (lane == 63) rbase = atomicAdd(nAllp, tot);
            rbase = __shfl(rbase, 63);
            int p = rbase + incl - cnt;
            #pragma unroll
            for (int k = 0; k < KRN; k++) {
                if (srow + 128 * k < ROWSPAN) {
                    unsigned int b = bits[k];
                    unsigned int uhi = (unsigned int)(srow + r0 + 128 * k) << 11;
                    while (b) {
                        int t = __ffs(b) - 1; b &= b - 1;
                        if (p < EACAP) eAll[p] = uhi | (unsigned int)(base + t);
                        p++;
                    }
                }
            }
        }
    }
    #pragma unroll
    for (int k = 0; k < KRN; k++)
        if (srow + 128 * k < ROWSPAN && rowdeg[k] > 0)
            atomicAdd(&sdeg[srow + r0 + 128 * k], rowdeg[k]);
}

// ---------------- per-group: adjacency + DBSCAN entirely in LDS --------------
// one block (1024 thr = 16 waves) per group; min 4 waves/EU declared so the
// VGPR cap is 128 (default 8 waves/EU capped at 64 -> forced scratch spills
// in R10/R11).
__global__ void __launch_bounds__(1024, 4) k_group(
        const float4* __restrict__ q, const int* __restrict__ grp,
        const float* __restrict__ x, float* __restrict__ out) {
    __shared__ float4 pts[NLCAP];                    // 24 KB
    __shared__ int nlist[NLCAP];                     // 6 KB (global idx, ASCENDING)
    __shared__ int sdeg[NLCAP];                      // 6 KB
    __shared__ int spar[NLCAP];                      // 6 KB (label -> later ccid)
    __shared__ int scid[NLCAP];                      // 6 KB
    __shared__ int sbmin[NLCAP];                     // 6 KB
    __shared__ unsigned int eAll[EACAP];             // 32 KB
    __shared__ unsigned int eL[ELCAP];               // 32 KB
    __shared__ unsigned int eB[EBCAP];               // 8 KB
    __shared__ unsigned long long corebm[NLCAP/64];  // 192 B
    __shared__ unsigned long long repbm[NLCAP/64];   // 192 B
    __shared__ int nNodes, nAll, nL, nB, sflag;

    const int g = blockIdx.x;
    const int tid = threadIdx.x, lane = tid & 63, wv = tid >> 6;

    if (tid == 0) { nNodes = 0; nAll = 0; nL = 0; nB = 0; }
    __syncthreads();

    // ordered node list (wave 0 serial ballot scan -> local order == index order)
    if (wv == 0) {
        int running = 0;
        for (int w = 0; w < NPTS / 64; w++) {
            int i = w * 64 + lane;
            bool ing = (grp[i] == g);
            unsigned long long bm = __ballot(ing);
            if (ing) {
                int p = running + __popcll(bm & ((1ull << lane) - 1ull));
                if (p < NLCAP) nlist[p] = i;
            }
            running += __popcll(bm);
        }
        if (lane == 0) nNodes = (running > NLCAP) ? NLCAP : running;
    }
    __syncthreads();
    const int NN = nNodes;

    // gather points; init state; sentinel-pad so pair loop needs no bounds checks
    for (int k = tid; k < NLCAP; k += 1024) {
        if (k < NN) {
            pts[k] = q[nlist[k]];
            sdeg[k] = 1;            // self-adjacency
            spar[k] = k;
            sbmin[k] = BIGC;
        } else {
            pts[k] = make_float4(0.f, 0.f, 0.f, 3.0e38f);  // d2 huge -> never adjacent
        }
    }
    __syncthreads();

    // ---- pair pass: main strip (rows < 1024) + guarded tail (1024..1535) ----
    const int NC = ((NN + 31) & ~31) >> 5;           // 32-wide v-chunks
    const int ROWSPAN = (NN + 127) & ~127;           // multiple of 128
    const int rep = tid >> 7;                        // replica 0..7 (chunk subset)
    const int r0  = tid & 127;

    pair_strip<8>(pts, eAll, sdeg, &nAll, 0, NC, ROWSPAN, rep, r0, lane);
    if (ROWSPAN > 1024)
        pair_strip<4>(pts, eAll, sdeg, &nAll, 1024, NC, ROWSPAN, rep, r0, lane);
    __syncthreads();
    const int NA = (nAll > EACAP) ? EACAP : nAll;

    // v-side degrees (scattered LDS atomics over ~820 addresses)
    for (int e = tid; e < NA; e += 1024)
        atomicAdd(&sdeg[eAll[e] & 2047u], 1);
    __syncthreads();

    // core bitmap (local indices)
    for (int w = wv; w < NLCAP / 64; w += 16) {
        int l = w * 64 + lane;
        bool isc = (l < NN) && (sdeg[l] >= MIN_PTS);
        unsigned long long bm = __ballot(isc);
        if (lane == 0) corebm[w] = bm;
    }
    __syncthreads();
    auto corebit = [&](int l) -> bool { return (corebm[l >> 6] >> (l & 63)) & 1ull; };

    // classify eAll -> eL (core-core) / eB (core-noncore), wave-aggregated
    for (int e0 = 0; e0 < NA; e0 += 1024) {
        int e = e0 + tid;
        unsigned int pk = (e < NA) ? eAll[e] : 0u;
        bool val = (e < NA);
        int u = (int)(pk >> 11), v = (int)(pk & 2047u);
        bool cu = val && corebit(u), cv = val && corebit(v);
        bool isL = cu && cv, isB = val && (cu != cv);
        unsigned long long mL = __ballot(isL);
        if (mL) {
            int b0 = 0;
            if (lane == 0) b0 = atomicAdd(&nL, __popcll(mL));
            b0 = __shfl(b0, 0);
            if (isL) {
                int idx = b0 + __popcll(mL & ((1ull << lane) - 1ull));
                if (idx < ELCAP) eL[idx] = pk;
            }
        }
        unsigned long long mB = __ballot(isB);
        if (mB) {
            int b0 = 0;
            if (lane == 0) b0 = atomicAdd(&nB, __popcll(mB));
            b0 = __shfl(b0, 0);
            if (isB) {
                int idx = b0 + __popcll(mB & ((1ull << lane) - 1ull));
                if (idx < EBCAP) eB[idx] = pk;
            }
        }
    }
    __syncthreads();
    const int NL = (nL > ELCAP) ? ELCAP : nL;
    const int NB = (nB > EBCAP) ? EBCAP : nB;

    // SV rounds: hook-to-min + pointer jump (fixpoint = component min index)
    for (int r = 0; r < ROUNDS; r++) {
        if (tid == 0) sflag = 0;
        __syncthreads();
        for (int k = tid; k < NL; k += 1024) {
            unsigned int pk = eL[k];
            int u = (int)(pk >> 11), v = (int)(pk & 2047u);
            int a = spar[u], b2 = spar[v];
            if (a < b2)      { int old = atomicMin(&spar[v], a);  if (old > a)  sflag = 1; }
            else if (b2 < a) { int old = atomicMin(&spar[u], b2); if (old > b2) sflag = 1; }
        }
        __syncthreads();
        for (int k = tid; k < NN; k += 1024) {
            int s = spar[k]; int s2 = spar[s];
            if (s2 < s) { spar[k] = s2; sflag = 1; }
        }
        __syncthreads();
        if (!sflag) break;
    }

    // reps + rank (local order == global index order -> cid = rank among reps)
    for (int w = wv; w < NLCAP / 64; w += 16) {
        int l = w * 64 + lane;
        bool isr = (l < NN) && corebit(l) && (spar[l] == l);
        unsigned long long bm = __ballot(isr);
        if (lane == 0) repbm[w] = bm;
    }
    __syncthreads();
    if (wv == 0) {
        int running = 0;
        for (int w = 0; w < NLCAP / 64; w++) {
            unsigned long long bm = repbm[w];
            if ((bm >> lane) & 1ull)
                scid[w * 64 + lane] = running + __popcll(bm & ((1ull << lane) - 1ull));
            running += __popcll(bm);
        }
    }
    __syncthreads();
    // ccid -> overwrite spar
    int cc[2];
    #pragma unroll
    for (int t = 0; t < 2; t++) {
        int k = tid + t * 1024;
        cc[t] = (k < NN && corebit(k)) ? scid[spar[k]] : BIGC;
    }
    __syncthreads();
    #pragma unroll
    for (int t = 0; t < 2; t++) {
        int k = tid + t * 1024;
        if (k < NN) spar[k] = cc[t];
    }
    __syncthreads();
    // border: min adjacent core cid for the non-core endpoint
    for (int k = tid; k < NB; k += 1024) {
        unsigned int pk = eB[k];
        int u = (int)(pk >> 11), v = (int)(pk & 2047u);
        int cu = spar[u], cv = spar[v];
        if (cu == BIGC) atomicMin(&sbmin[u], cv);
        else            atomicMin(&sbmin[v], cu);
    }
    __syncthreads();
    // final labels + clustered output for this group's nodes
    for (int k = tid; k < NN; k += 1024) {
        int i = nlist[k];
        int c = spar[k];
        int lbl = (c != BIGC) ? c : ((sbmin[k] < BIGC) ? sbmin[k] : -1);
        out[i] = (float)lbl;
        const float* r = x + (size_t)i * XCOLS;
        float* o = out + NPTS + (size_t)i * 5;
        bool keep = lbl >= 0;
        #pragma unroll
        for (int c5 = 0; c5 < 5; c5++) o[c5] = keep ? r[c5] : 0.0f;
    }
}

extern "C" void kernel_launch(void* const* d_in, const int* in_sizes, int n_in,
                              void* d_out, int out_size, void* d_ws, size_t ws_size,
                              hipStream_t stream) {
    const float* x = (const float*)d_in[0];
    float* out = (float*)d_out;
    char* ws = (char*)d_ws;

    // workspace: 164 KB total
    float4* q = (float4*)(ws);               // 131072 B
    int* grp  = (int*)(ws + 131072);         // 32768 B

    k_setup<<<NPTS / 256, 256, 0, stream>>>(x, q, grp);
    k_group<<<NGROUPS, 1024, 0, stream>>>(q, grp, x, out);
}

// Round 13
// 103.134 us; speedup vs baseline: 1.6501x; 1.6501x over previous
//
#include <hip/hip_runtime.h>
#include <cstdint>
#include <cstddef>

#define NPTS 8192
#define NUM_CLASSES 5
#define XCOLS 10          // 3 coords + batch + feat + 5 seg
#define EPS2 225.0f
#define MIN_PTS 5
#define NGROUPS 10
#define BIGC 0x3fffffff

#define NLCAP 1536        // max nodes per group (expect ~820)
#define EACAP 8192        // per-group eps-pairs u<v (expect ~5.4k)
#define ELCAP 8192        // core-core edges
#define EBCAP 2048        // core-noncore edges (expect ~500)
#define CPAD 64           // per-group edge counters padded 256 B apart
#define NSLICE 8          // row slices per group in k_pairs
#define KR 3              // rows per lane in k_pairs (3*64*8 = 1536 = NLCAP)
#define ROUNDS 16

// ---------------- setup: pack coords+p2, group, zero edge counters -----------
__global__ void k_setup(const float* __restrict__ x, float4* __restrict__ q,
                        int* __restrict__ grp, unsigned int* __restrict__ gcnt) {
    int i = blockIdx.x * blockDim.x + threadIdx.x;
    if (i < NGROUPS * CPAD) gcnt[i] = 0u;
    if (i >= NPTS) return;
    const float* r = x + (size_t)i * XCOLS;
    float px = r[0], py = r[1], pz = r[2];
    int b = (int)r[3];
    float best = r[5]; int bc = 0;
    #pragma unroll
    for (int c = 1; c < NUM_CLASSES; c++) {
        float v = r[5 + c];
        if (v > best) { best = v; bc = c; }   // strict > keeps first max (jnp.argmax)
    }
    q[i] = make_float4(px, py, pz, px*px + py*py + pz*pz);
    grp[i] = b * NUM_CLASSES + bc;
}

// ---------------- nodes: ordered per-group node list (parallel prefix) -------
__global__ void __launch_bounds__(1024) k_nodes(
        const int* __restrict__ grp, int* __restrict__ nlist_g,
        int* __restrict__ nn_g) {
    __shared__ unsigned long long masks[NPTS / 64];   // 128 words
    __shared__ int pref[NPTS / 64];
    __shared__ int nnS;
    const int g = blockIdx.x;
    const int tid = threadIdx.x, lane = tid & 63, wv = tid >> 6;

    for (int w = wv; w < NPTS / 64; w += 16) {
        int i = w * 64 + lane;
        unsigned long long bm = __ballot(grp[i] == g);
        if (lane == 0) masks[w] = bm;
    }
    __syncthreads();
    if (wv == 0) {                         // 2-chunk scan of 128 popcounts
        int v0 = __popcll(masks[lane]);
        int incl = v0;
        #pragma unroll
        for (int s = 1; s < 64; s <<= 1) {
            int o = __shfl_up(incl, s);
            if (lane >= s) incl += o;
        }
        pref[lane] = incl - v0;
        int tot0 = __shfl(incl, 63);
        int v1 = __popcll(masks[64 + lane]);
        int incl1 = v1;
        #pragma unroll
        for (int s = 1; s < 64; s <<= 1) {
            int o = __shfl_up(incl1, s);
            if (lane >= s) incl1 += o;
        }
        pref[64 + lane] = tot0 + incl1 - v1;
        if (lane == 63) nnS = tot0 + incl1;
    }
    __syncthreads();
    for (int w = wv; w < NPTS / 64; w += 16) {
        int i = w * 64 + lane;
        unsigned long long bm = masks[w];
        if ((bm >> lane) & 1ull) {
            int p = pref[w] + __popcll(bm & ((1ull << lane) - 1ull));
            if (p < NLCAP) nlist_g[g * NLCAP + p] = i;
        }
    }
    if (tid == 0) nn_g[g] = (nnS > NLCAP) ? NLCAP : nnS;
}

// ---------------- pairs: per-(group,slice) adjacency -> global edges + deg ---
// grid = 10*8; block 256 (4 waves). Wave w owns chunks c==w (mod 4); lane owns
// rows s+8*(lane+64k), k<KR (compile-time -> registers). Each ds_read feeds
// 64 lanes x 3 rows.
__global__ void __launch_bounds__(256) k_pairs(
        const float4* __restrict__ q, const int* __restrict__ nlist_g,
        const int* __restrict__ nn_g, unsigned int* __restrict__ eAll_g,
        unsigned int* __restrict__ gcnt, int* __restrict__ deg_g) {
    __shared__ float4 pts[NLCAP];          // 24 KB
    __shared__ int srowdeg[NLCAP / NSLICE];// 192 rows this slice
    const int g = blockIdx.x / NSLICE;
    const int s = blockIdx.x % NSLICE;
    const int tid = threadIdx.x, lane = tid & 63, wq = tid >> 6;
    const int nn = nn_g[g];

    for (int k = tid; k < NLCAP; k += 256)
        pts[k] = (k < nn) ? q[nlist_g[g * NLCAP + k]]
                          : make_float4(0.f, 0.f, 0.f, 3.0e38f);
    for (int m = tid; m < NLCAP / NSLICE; m += 256) srowdeg[m] = 0;
    __syncthreads();

    int rrow[KR]; float4 qu[KR]; int rowdeg[KR];
    #pragma unroll
    for (int k = 0; k < KR; k++) {
        rrow[k] = s + 8 * (lane + 64 * k);           // < 1536
        qu[k] = pts[rrow[k]];
        rowdeg[k] = 0;
    }

    const int NC = (nn + 31) >> 5;
    unsigned int* eg = eAll_g + (size_t)g * EACAP;
    for (int c = wq; c < NC; c += 4) {
        int base = c << 5;
        unsigned int bits[KR];
        #pragma unroll
        for (int k = 0; k < KR; k++) bits[k] = 0u;
        #pragma unroll
        for (int t = 0; t < 32; t++) {
            float4 qv = pts[base + t];               // wave-uniform broadcast
            #pragma unroll
            for (int k = 0; k < KR; k++) {
                float d2 = qu[k].w + qv.w - 2.0f * (qu[k].x*qv.x + qu[k].y*qv.y + qu[k].z*qv.z);
                bits[k] |= (d2 < EPS2) ? (1u << t) : 0u;
            }
        }
        int cnt = 0;
        #pragma unroll
        for (int k = 0; k < KR; k++) {
            int d = rrow[k] - base;                  // keep only v > u
            if (d >= 31) bits[k] = 0u;
            else if (d >= 0) bits[k] &= ~((2u << d) - 1u);
            int pc = __popc(bits[k]);
            rowdeg[k] += pc;
            cnt += pc;
        }
        int incl = cnt;
        #pragma unroll
        for (int st = 1; st < 64; st <<= 1) {
            int o = __shfl_up(incl, st);
            if (lane >= st) incl += o;
        }
        int tot = __shfl(incl, 63);
        if (tot > 0) {
            unsigned int rbase = 0;
            if (lane == 63) rbase = atomicAdd(&gcnt[g * CPAD], (unsigned int)tot);
            rbase = __shfl(rbase, 63);
            unsigned int p = rbase + (unsigned int)(incl - cnt);
            #pragma unroll
            for (int k = 0; k < KR; k++) {
                unsigned int b = bits[k];
                unsigned int uhi = (unsigned int)rrow[k] << 11;
                while (b) {
                    int t = __ffs(b) - 1; b &= b - 1;
                    if (p < EACAP) eg[p] = uhi | (unsigned int)(base + t);
                    p++;
                }
            }
        }
    }
    #pragma unroll
    for (int k = 0; k < KR; k++)
        if (rowdeg[k] > 0) atomicAdd(&srowdeg[lane + 64 * k], rowdeg[k]);
    __syncthreads();
    // this block is the unique owner of rows r==s (mod 8): plain store
    for (int m = tid; m < NLCAP / NSLICE; m += 256)
        deg_g[g * NLCAP + s + 8 * m] = 1 + srowdeg[m];   // +1 self-adjacency
}

// ---------------- graph: deg -> core -> SV -> rank -> border -> output -------
__global__ void __launch_bounds__(1024) k_graph(
        const unsigned int* __restrict__ eAll_g, const unsigned int* __restrict__ gcnt,
        const int* __restrict__ deg_g, const int* __restrict__ nlist_g,
        const int* __restrict__ nn_g, const float* __restrict__ x,
        float* __restrict__ out) {
    __shared__ unsigned int eA[EACAP];               // 32 KB
    __shared__ unsigned int eL[ELCAP];               // 32 KB
    __shared__ unsigned int eB[EBCAP];               // 8 KB
    __shared__ int sdeg[NLCAP];                      // 6 KB
    __shared__ int spar[NLCAP];                      // 6 KB
    __shared__ int scid[NLCAP];                      // 6 KB
    __shared__ int sbmin[NLCAP];                     // 6 KB
    __shared__ int nlist[NLCAP];                     // 6 KB
    __shared__ unsigned long long corebm[NLCAP/64];  // 192 B
    __shared__ unsigned long long repbm[NLCAP/64];   // 192 B
    __shared__ int nL, nB, sflag;

    const int g = blockIdx.x;
    const int tid = threadIdx.x, lane = tid & 63, wv = tid >> 6;
    const int NN = nn_g[g];
    unsigned int Eu = gcnt[g * CPAD];
    const int NA = (Eu > (unsigned)EACAP) ? EACAP : (int)Eu;

    if (tid == 0) { nL = 0; nB = 0; }
    for (int k = tid; k < NLCAP; k += 1024) {
        sdeg[k] = deg_g[g * NLCAP + k];
        spar[k] = k;
        sbmin[k] = BIGC;
        nlist[k] = nlist_g[g * NLCAP + k];
    }
    for (int e = tid; e < NA; e += 1024) eA[e] = eAll_g[(size_t)g * EACAP + e];
    __syncthreads();
    // v-side degrees
    for (int e = tid; e < NA; e += 1024) atomicAdd(&sdeg[eA[e] & 2047u], 1);
    __syncthreads();
    // core bitmap
    for (int w = wv; w < NLCAP / 64; w += 16) {
        int l = w * 64 + lane;
        bool isc = (l < NN) && (sdeg[l] >= MIN_PTS);
        unsigned long long bm = __ballot(isc);
        if (lane == 0) corebm[w] = bm;
    }
    __syncthreads();
    auto corebit = [&](int l) -> bool { return (corebm[l >> 6] >> (l & 63)) & 1ull; };

    // classify eA -> eL / eB (wave-aggregated)
    for (int e0 = 0; e0 < NA; e0 += 1024) {
        int e = e0 + tid;
        unsigned int pk = (e < NA) ? eA[e] : 0u;
        bool val = (e < NA);
        int u = (int)(pk >> 11), v = (int)(pk & 2047u);
        bool cu = val && corebit(u), cv = val && corebit(v);
        bool isL = cu && cv, isB = val && (cu != cv);
        unsigned long long mL = __ballot(isL);
        if (mL) {
            int b0 = 0;
            if (lane == 0) b0 = atomicAdd(&nL, __popcll(mL));
            b0 = __shfl(b0, 0);
            if (isL) {
                int idx = b0 + __popcll(mL & ((1ull << lane) - 1ull));
                if (idx < ELCAP) eL[idx] = pk;
            }
        }
        unsigned long long mB = __ballot(isB);
        if (mB) {
            int b0 = 0;
            if (lane == 0) b0 = atomicAdd(&nB, __popcll(mB));
            b0 = __shfl(b0, 0);
            if (isB) {
                int idx = b0 + __popcll(mB & ((1ull << lane) - 1ull));
                if (idx < EBCAP) eB[idx] = pk;
            }
        }
    }
    __syncthreads();
    const int NL = (nL > ELCAP) ? ELCAP : nL;
    const int NB = (nB > EBCAP) ? EBCAP : nB;

    // SV rounds: hook-to-min + DOUBLE pointer jump
    for (int r = 0; r < ROUNDS; r++) {
        if (tid == 0) sflag = 0;
        __syncthreads();
        for (int k = tid; k < NL; k += 1024) {
            unsigned int pk = eL[k];
            int u = (int)(pk >> 11), v = (int)(pk & 2047u);
            int a = spar[u], b2 = spar[v];
            if (a < b2)      { int old = atomicMin(&spar[v], a);  if (old > a)  sflag = 1; }
            else if (b2 < a) { int old = atomicMin(&spar[u], b2); if (old > b2) sflag = 1; }
        }
        __syncthreads();
        for (int k = tid; k < NN; k += 1024) {
            int s = spar[k]; int s2 = spar[s];
            if (s2 < s) { s = spar[s2]; spar[k] = (s < s2) ? s : s2; sflag = 1; }
        }
        __syncthreads();
        if (!sflag) break;
    }

    // reps + rank (wave 0 serial over 24 words)
    for (int w = wv; w < NLCAP / 64; w += 16) {
        int l = w * 64 + lane;
        bool isr = (l < NN) && corebit(l) && (spar[l] == l);
        unsigned long long bm = __ballot(isr);
        if (lane == 0) repbm[w] = bm;
    }
    __syncthreads();
    if (wv == 0) {
        int running = 0;
        for (int w = 0; w < NLCAP / 64; w++) {
            unsigned long long bm = repbm[w];
            if ((bm >> lane) & 1ull)
                scid[w * 64 + lane] = running + __popcll(bm & ((1ull << lane) - 1ull));
            running += __popcll(bm);
        }
    }
    __syncthreads();
    // ccid -> overwrite spar
    int cc[2];
    #pragma unroll
    for (int t = 0; t < 2; t++) {
        int k = tid + t * 1024;
        cc[t] = (k < NN && corebit(k)) ? scid[spar[k]] : BIGC;
    }
    __syncthreads();
    #pragma unroll
    for (int t = 0; t < 2; t++) {
        int k = tid + t * 1024;
        if (k < NN) spar[k] = cc[t];
    }
    __syncthreads();
    // border: min adjacent core cid for the non-core endpoint
    for (int k = tid; k < NB; k += 1024) {
        unsigned int pk = eB[k];
        int u = (int)(pk >> 11), v = (int)(pk & 2047u);
        int cu = spar[u], cv = spar[v];
        if (cu == BIGC) atomicMin(&sbmin[u], cv);
        else            atomicMin(&sbmin[v], cu);
    }
    __syncthreads();
    // final labels + clustered output
    for (int k = tid; k < NN; k += 1024) {
        int i = nlist[k];
        int c = spar[k];
        int lbl = (c != BIGC) ? c : ((sbmin[k] < BIGC) ? sbmin[k] : -1);
        out[i] = (float)lbl;
        const float* r = x + (size_t)i * XCOLS;
        float* o = out + NPTS + (size_t)i * 5;
        bool keep = lbl >= 0;
        #pragma unroll
        for (int c5 = 0; c5 < 5; c5++) o[c5] = keep ? r[c5] : 0.0f;
    }
}

extern "C" void kernel_launch(void* const* d_in, const int* in_sizes, int n_in,
                              void* d_out, int out_size, void* d_ws, size_t ws_size,
                              hipStream_t stream) {
    const float* x = (const float*)d_in[0];
    float* out = (float*)d_out;
    char* ws = (char*)d_ws;

    // workspace layout (~660 KB)
    float4* q           = (float4*)(ws);                  // 131072 B
    int* grp            = (int*)(ws + 131072);            // 32768
    unsigned int* gcnt  = (unsigned int*)(ws + 163840);   // 10*64*4 = 2560
    int* nn_g           = (int*)(ws + 166400);            // 64
    int* nlist_g        = (int*)(ws + 166464);            // 10*1536*4 = 61440
    int* deg_g          = (int*)(ws + 227904);            // 61440
    unsigned int* eAll_g= (unsigned int*)(ws + 289344);   // 10*8192*4 = 327680

    k_setup<<<NPTS / 256, 256, 0, stream>>>(x, q, grp, gcnt);
    k_nodes<<<NGROUPS, 1024, 0, stream>>>(grp, nlist_g, nn_g);
    k_pairs<<<NGROUPS * NSLICE, 256, 0, stream>>>(q, nlist_g, nn_g, eAll_g, gcnt, deg_g);
    k_graph<<<NGROUPS, 1024, 0, stream>>>(eAll_g, gcnt, deg_g, nlist_g, nn_g, x, out);
}